// Round 1
// baseline (201.331 us; speedup 1.0000x reference)
//
#include <hip/hip_runtime.h>

typedef _Float16 f16;
typedef _Float16 f16x8 __attribute__((ext_vector_type(8)));
typedef _Float16 f16x4 __attribute__((ext_vector_type(4)));
typedef float f32x4 __attribute__((ext_vector_type(4)));

#define MFMA(a, b, c) __builtin_amdgcn_mfma_f32_16x16x32_f16(a, b, c, 0, 0, 0)

// B=2, T=2048, D=1024, H=16, DH=64

// ---------- prep: fp32 -> fp16 convert of hidden ----------
__global__ __launch_bounds__(256) void k_cvt_hidden(const float* __restrict__ x, f16* __restrict__ y) {
  int i = blockIdx.x * 256 + threadIdx.x;   // exactly 4096*256 threads, 4 floats each
  float4 v = ((const float4*)x)[i];
  f16x4 h; h[0] = (f16)v.x; h[1] = (f16)v.y; h[2] = (f16)v.z; h[3] = (f16)v.w;
  ((f16x4*)y)[i] = h;
}

// ---------- prep: transpose+convert weights [k][n] fp32 -> [n][k] fp16 ----------
__global__ __launch_bounds__(256) void k_cvt_w(const float* __restrict__ w0, const float* __restrict__ w1,
                                               const float* __restrict__ w2, const float* __restrict__ w3,
                                               f16* __restrict__ wt) {
  int z = blockIdx.z;
  const float* w = z == 0 ? w0 : z == 1 ? w1 : z == 2 ? w2 : w3;
  f16* dst = wt + (size_t)z * 1024 * 1024;
  __shared__ float tile[64][65];
  int t = threadIdx.x;
  int k0 = blockIdx.x * 64, n0 = blockIdx.y * 64;
  int cr = t >> 4, cc = (t & 15) * 4;
#pragma unroll
  for (int p = 0; p < 4; p++) {
    int r = cr + p * 16;
    float4 v = *(const float4*)&w[(size_t)(k0 + r) * 1024 + n0 + cc];
    tile[r][cc + 0] = v.x; tile[r][cc + 1] = v.y; tile[r][cc + 2] = v.z; tile[r][cc + 3] = v.w;
  }
  __syncthreads();
#pragma unroll
  for (int p = 0; p < 4; p++) {
    int nn = cr + p * 16;
    f16x4 h;
    h[0] = (f16)tile[cc + 0][nn]; h[1] = (f16)tile[cc + 1][nn];
    h[2] = (f16)tile[cc + 2][nn]; h[3] = (f16)tile[cc + 3][nn];
    *(f16x4*)&dst[(size_t)(n0 + nn) * 1024 + k0 + cc] = h;
  }
}

// ---------- GEMM core: C[M,N] = A[M,K] @ W^T stored [N,K], fp16 in, fp32 acc ----------
// 128x128 tile, BK=64, 4 waves each 64x64 (4x4 MFMA 16x16x32), XOR-swizzled LDS.
template <bool OUTF32>
__device__ __forceinline__ void gemm_core(const f16* __restrict__ A, const f16* __restrict__ W,
                                          const float* __restrict__ bias,
                                          f16* __restrict__ oh, float* __restrict__ of) {
  __shared__ f16 Al[128 * 64];
  __shared__ f16 Bl[128 * 64];
  const int t = threadIdx.x;
  const int lane = t & 63, wid = t >> 6;
  const int lr = lane & 15, lg = lane >> 4;
  const int m0 = blockIdx.x * 128, n0 = blockIdx.y * 128;
  const int wm = wid >> 1, wn = wid & 1;
  const int srow = t >> 3;
  const int scb = (t & 7) << 4;   // staging byte col
  const int sk = (t & 7) << 3;    // staging k offset (halves)

  f32x4 acc[4][4] = {};

  for (int k0 = 0; k0 < 1024; k0 += 64) {
    __syncthreads();
#pragma unroll
    for (int it = 0; it < 4; it++) {
      int row = it * 32 + srow;
      f16x8 va = *(const f16x8*)&A[(size_t)(m0 + row) * 1024 + k0 + sk];
      f16x8 vb = *(const f16x8*)&W[(size_t)(n0 + row) * 1024 + k0 + sk];
      int o = row * 128 + (scb ^ ((row & 7) << 4));
      *(f16x8*)((char*)Al + o) = va;
      *(f16x8*)((char*)Bl + o) = vb;
    }
    __syncthreads();
    f16x8 af[2][4], bf[2][4];
#pragma unroll
    for (int x = 0; x < 4; x++) {
      int ra = wm * 64 + x * 16 + lr;
      int rb = wn * 64 + x * 16 + lr;
#pragma unroll
      for (int kh = 0; kh < 2; kh++) {
        int ca = (kh * 64 + lg * 16) ^ ((lr & 7) << 4);  // row&7 == lr&7
        af[kh][x] = *(const f16x8*)((char*)Al + ra * 128 + ca);
        bf[kh][x] = *(const f16x8*)((char*)Bl + rb * 128 + ca);
      }
    }
#pragma unroll
    for (int kh = 0; kh < 2; kh++)
#pragma unroll
      for (int mt = 0; mt < 4; mt++)
#pragma unroll
        for (int nt = 0; nt < 4; nt++)
          acc[mt][nt] = MFMA(af[kh][mt], bf[kh][nt], acc[mt][nt]);
  }
#pragma unroll
  for (int mt = 0; mt < 4; mt++) {
#pragma unroll
    for (int nt = 0; nt < 4; nt++) {
      int col = n0 + wn * 64 + nt * 16 + lr;
      float bcol = bias[col];
#pragma unroll
      for (int e = 0; e < 4; e++) {
        int row = m0 + wm * 64 + mt * 16 + lg * 4 + e;
        float val = acc[mt][nt][e] + bcol;
        if (OUTF32) of[(size_t)row * 1024 + col] = val;
        else        oh[(size_t)row * 1024 + col] = (f16)val;
      }
    }
  }
}

__global__ __launch_bounds__(256, 2) void k_gemm_qkv(const f16* __restrict__ A, const f16* __restrict__ wt,
                                                     const float* __restrict__ bq, const float* __restrict__ bk,
                                                     const float* __restrict__ bv,
                                                     f16* __restrict__ q, f16* __restrict__ k, f16* __restrict__ v) {
  int z = blockIdx.z;
  gemm_core<false>(A, wt + (size_t)z * 1024 * 1024,
                   z == 0 ? bq : z == 1 ? bk : bv,
                   z == 0 ? q : z == 1 ? k : v, nullptr);
}

__global__ __launch_bounds__(256, 2) void k_gemm_o(const f16* __restrict__ A, const f16* __restrict__ wt,
                                                   const float* __restrict__ bo, float* __restrict__ out) {
  gemm_core<true>(A, wt, bo, nullptr, out);
}

// ---------- RMSNorm + interleaved RoPE (in-place on fp16 q/k), fp32 math ----------
__global__ __launch_bounds__(256) void k_normrope(f16* __restrict__ qh, f16* __restrict__ kh,
                                                  const float* __restrict__ gq, const float* __restrict__ gk,
                                                  const float* __restrict__ cs, const float* __restrict__ sn) {
  int row = blockIdx.x, which = blockIdx.y;
  f16* buf = which ? kh : qh;
  const float* g = which ? gk : gq;
  int t = threadIdx.x, c4 = t * 4;
  f16x4 xv = *(const f16x4*)&buf[(size_t)row * 1024 + c4];
  float x0 = xv[0], x1 = xv[1], x2 = xv[2], x3 = xv[3];
  float ss = x0 * x0 + x1 * x1 + x2 * x2 + x3 * x3;
#pragma unroll
  for (int off = 1; off < 64; off <<= 1) ss += __shfl_xor(ss, off);
  __shared__ float red[4];
  if ((t & 63) == 0) red[t >> 6] = ss;
  __syncthreads();
  float inv = rsqrtf((red[0] + red[1] + red[2] + red[3]) * (1.0f / 1024.0f) + 1e-6f);
  int tt = row & 2047;
  float4 cv = *(const float4*)&cs[(size_t)tt * 1024 + c4];
  float4 sv = *(const float4*)&sn[(size_t)tt * 1024 + c4];
  float4 gv = *(const float4*)&g[c4];
  float y0 = x0 * inv * gv.x, y1 = x1 * inv * gv.y, y2 = x2 * inv * gv.z, y3 = x3 * inv * gv.w;
  f16x4 ov;
  ov[0] = (f16)(y0 * cv.x - y1 * sv.x);
  ov[1] = (f16)(y1 * cv.y + y0 * sv.y);
  ov[2] = (f16)(y2 * cv.z - y3 * sv.z);
  ov[3] = (f16)(y3 * cv.w + y2 * sv.w);
  *(f16x4*)&buf[(size_t)row * 1024 + c4] = ov;
}

// ---------- V transpose: [b,t,h*64+dh] -> [b,h,dh,t] ----------
__global__ __launch_bounds__(256) void k_vtrans(const f16* __restrict__ vh, f16* __restrict__ vt) {
  __shared__ f16 tile[64][65];
  int t = threadIdx.x;
  int t0 = blockIdx.x * 64;
  int bh = blockIdx.y;
  int b = bh >> 4, h = bh & 15;
  int rr = t >> 3, c8 = (t & 7) * 8;
#pragma unroll
  for (int p = 0; p < 2; p++) {
    int r = p * 32 + rr;
    f16x8 v = *(const f16x8*)&vh[(size_t)(b * 2048 + t0 + r) * 1024 + h * 64 + c8];
#pragma unroll
    for (int j = 0; j < 8; j++) tile[r][c8 + j] = v[j];
  }
  __syncthreads();
#pragma unroll
  for (int p = 0; p < 2; p++) {
    int dh = p * 32 + rr;
    f16x8 o;
#pragma unroll
    for (int j = 0; j < 8; j++) o[j] = tile[c8 + j][dh];
    *(f16x8*)&vt[((size_t)bh * 64 + dh) * 2048 + t0 + c8] = o;
  }
}

// ---------- flash attention: per block 64 q-rows (4 waves x 16), KV-chunk 64 ----------
__global__ __launch_bounds__(256, 2) void k_attn(const f16* __restrict__ qh, const f16* __restrict__ kh,
                                                 const f16* __restrict__ vt, f16* __restrict__ ao) {
  __shared__ f16 Kl[64 * 64];
  __shared__ f16 Vl[64 * 64];
  __shared__ f16 Pl[4][1024];
  const int t = threadIdx.x;
  const int lane = t & 63, wid = t >> 6;
  const int lr = lane & 15, lg = lane >> 4;
  const int b = blockIdx.y >> 4, h = blockIdx.y & 15;
  const int q0 = blockIdx.x * 64 + wid * 16;
  const f16* Qb = qh + ((size_t)(b * 2048 + q0)) * 1024 + h * 64;
  f16x8 qf0 = *(const f16x8*)&Qb[(size_t)lr * 1024 + lg * 8];
  f16x8 qf1 = *(const f16x8*)&Qb[(size_t)lr * 1024 + 32 + lg * 8];
  const f16* Kg = kh + ((size_t)b * 2048) * 1024 + h * 64;
  const f16* Vg = vt + ((size_t)blockIdx.y) * 64 * 2048;
  const int srow = t >> 3, scb = (t & 7) << 4, sk = (t & 7) << 3;
  const float sc = 0.125f * 1.44269504088896340736f;  // scale * log2(e), exp2 domain
  float m[4] = {-1e30f, -1e30f, -1e30f, -1e30f};
  float l[4] = {0.f, 0.f, 0.f, 0.f};
  f32x4 acc[4] = {};
  char* Plw = (char*)&Pl[wid][0];

  for (int kv0 = 0; kv0 < 2048; kv0 += 64) {
    __syncthreads();
#pragma unroll
    for (int it = 0; it < 2; it++) {
      int row = it * 32 + srow;
      f16x8 vk = *(const f16x8*)&Kg[(size_t)(kv0 + row) * 1024 + sk];
      f16x8 vv = *(const f16x8*)&Vg[(size_t)row * 2048 + kv0 + sk];
      int o = row * 128 + (scb ^ ((row & 7) << 4));
      *(f16x8*)((char*)Kl + o) = vk;
      *(f16x8*)((char*)Vl + o) = vv;
    }
    __syncthreads();

    // S = Q K^T for 64 keys (4 subtiles of 16)
    f32x4 s[4];
#pragma unroll
    for (int ks = 0; ks < 4; ks++) {
      int row = ks * 16 + lr;
      int c0 = (lg * 16) ^ ((lr & 7) << 4);
      int c1 = (64 + lg * 16) ^ ((lr & 7) << 4);
      f16x8 kf0 = *(const f16x8*)((char*)Kl + row * 128 + c0);
      f16x8 kf1 = *(const f16x8*)((char*)Kl + row * 128 + c1);
      f32x4 z = {};
      z = MFMA(qf0, kf0, z);
      z = MFMA(qf1, kf1, z);
      s[ks] = z;
    }

    // online softmax (rows = lg*4+e, reduce across lr lanes)
    float al[4], sum[4];
#pragma unroll
    for (int e = 0; e < 4; e++) {
      float v = fmaxf(fmaxf(s[0][e], s[1][e]), fmaxf(s[2][e], s[3][e])) * sc;
#pragma unroll
      for (int off = 1; off < 16; off <<= 1) v = fmaxf(v, __shfl_xor(v, off));
      float mn = fmaxf(m[e], v);
      al[e] = exp2f(m[e] - mn);
      m[e] = mn;
      sum[e] = 0.f;
    }
#pragma unroll
    for (int ks = 0; ks < 4; ks++) {
#pragma unroll
      for (int e = 0; e < 4; e++) {
        float p = exp2f(s[ks][e] * sc - m[e]);
        sum[e] += p;
        int rrow = lg * 4 + e;
        *(f16*)(Plw + rrow * 128 + (((ks * 16 + lr) << 1) ^ ((rrow & 7) << 4))) = (f16)p;
      }
    }
#pragma unroll
    for (int e = 0; e < 4; e++) {
      float sv = sum[e];
#pragma unroll
      for (int off = 1; off < 16; off <<= 1) sv += __shfl_xor(sv, off);
      l[e] = l[e] * al[e] + sv;
#pragma unroll
      for (int ds = 0; ds < 4; ds++) acc[ds][e] *= al[e];
    }

    // PV
    int pc0 = (lg * 16) ^ ((lr & 7) << 4);
    int pc1 = (64 + lg * 16) ^ ((lr & 7) << 4);
    f16x8 pf0 = *(const f16x8*)(Plw + lr * 128 + pc0);
    f16x8 pf1 = *(const f16x8*)(Plw + lr * 128 + pc1);
#pragma unroll
    for (int ds = 0; ds < 4; ds++) {
      int row = ds * 16 + lr;
      f16x8 vf0 = *(const f16x8*)((char*)Vl + row * 128 + pc0);
      f16x8 vf1 = *(const f16x8*)((char*)Vl + row * 128 + pc1);
      acc[ds] = MFMA(pf0, vf0, acc[ds]);
      acc[ds] = MFMA(pf1, vf1, acc[ds]);
    }
  }

#pragma unroll
  for (int e = 0; e < 4; e++) {
    float linv = 1.f / l[e];
    size_t row = (size_t)(b * 2048 + q0 + lg * 4 + e);
#pragma unroll
    for (int ds = 0; ds < 4; ds++)
      ao[row * 1024 + h * 64 + ds * 16 + lr] = (f16)(acc[ds][e] * linv);
  }
}

extern "C" void kernel_launch(void* const* d_in, const int* in_sizes, int n_in,
                              void* d_out, int out_size, void* d_ws, size_t ws_size,
                              hipStream_t stream) {
  const float* hid  = (const float*)d_in[0];
  const float* cosb = (const float*)d_in[1];
  const float* sinb = (const float*)d_in[2];
  const float* wq = (const float*)d_in[3];
  const float* bq = (const float*)d_in[4];
  const float* wk = (const float*)d_in[5];
  const float* bk = (const float*)d_in[6];
  const float* wv = (const float*)d_in[7];
  const float* bv = (const float*)d_in[8];
  const float* gq = (const float*)d_in[9];
  const float* gk = (const float*)d_in[10];
  const float* wo = (const float*)d_in[11];
  const float* bo = (const float*)d_in[12];
  float* out = (float*)d_out;

  char* ws = (char*)d_ws;
  f16* aH  = (f16*)(ws);                          // 8 MB: hidden fp16 [4096][1024]
  f16* wt  = (f16*)(ws + ((size_t)8 << 20));      // 8 MB: 4 weights transposed [n][k] fp16
  f16* qh  = (f16*)(ws + ((size_t)16 << 20));     // 8 MB
  f16* khb = (f16*)(ws + ((size_t)24 << 20));     // 8 MB
  f16* vhb = (f16*)(ws + ((size_t)32 << 20));     // 8 MB
  f16* vtb = (f16*)(ws + ((size_t)40 << 20));     // 8 MB: V^T [b,h,dh,t]
  f16* ao  = (f16*)(ws + ((size_t)48 << 20));     // 8 MB: attention out [4096][1024]

  k_cvt_hidden<<<dim3(4096), dim3(256), 0, stream>>>(hid, aH);
  k_cvt_w<<<dim3(16, 16, 4), dim3(256), 0, stream>>>(wq, wk, wv, wo, wt);
  k_gemm_qkv<<<dim3(32, 8, 3), dim3(256), 0, stream>>>(aH, wt, bq, bk, bv, qh, khb, vhb);
  k_normrope<<<dim3(4096, 2), dim3(256), 0, stream>>>(qh, khb, gq, gk, cosb, sinb);
  k_vtrans<<<dim3(32, 32), dim3(256), 0, stream>>>(vhb, vtb);
  k_attn<<<dim3(32, 32), dim3(256), 0, stream>>>(qh, khb, vtb, ao);
  k_gemm_o<<<dim3(32, 8, 1), dim3(256), 0, stream>>>(ao, wt + (size_t)3 * 1024 * 1024, bo, out);
}

// Round 3
// 162.404 us; speedup vs baseline: 1.2397x; 1.2397x over previous
//
#include <hip/hip_runtime.h>

typedef _Float16 f16;
typedef _Float16 f16x8 __attribute__((ext_vector_type(8)));
typedef _Float16 f16x4 __attribute__((ext_vector_type(4)));
typedef _Float16 f16x2 __attribute__((ext_vector_type(2)));
typedef float f32x4 __attribute__((ext_vector_type(4)));

#define MFMA(a, b, c) __builtin_amdgcn_mfma_f32_16x16x32_f16(a, b, c, 0, 0, 0)
#define PKRTZ(a, b) __builtin_bit_cast(f16x2, __builtin_amdgcn_cvt_pkrtz(a, b))

__device__ __forceinline__ void gload16(const void* g, void* l) {
  __builtin_amdgcn_global_load_lds((const __attribute__((address_space(1))) char*)g,
                                   (__attribute__((address_space(3))) char*)l, 16, 0, 0);
}

// B=2, T=2048, D=1024, H=16, DH=64

// ---------- prep: fp32 -> fp16 convert of hidden ----------
__global__ __launch_bounds__(256) void k_cvt_hidden(const float* __restrict__ x, f16* __restrict__ y) {
  int i = blockIdx.x * 256 + threadIdx.x;
  float4 v = ((const float4*)x)[i];
  f16x4 h; h[0] = (f16)v.x; h[1] = (f16)v.y; h[2] = (f16)v.z; h[3] = (f16)v.w;
  ((f16x4*)y)[i] = h;
}

// ---------- prep: transpose+convert weights [k][n] fp32 -> [n][k] fp16 ----------
__global__ __launch_bounds__(256) void k_cvt_w(const float* __restrict__ w0, const float* __restrict__ w1,
                                               const float* __restrict__ w2, const float* __restrict__ w3,
                                               f16* __restrict__ wt) {
  int z = blockIdx.z;
  const float* w = z == 0 ? w0 : z == 1 ? w1 : z == 2 ? w2 : w3;
  f16* dst = wt + (size_t)z * 1024 * 1024;
  __shared__ float tile[64][65];
  int t = threadIdx.x;
  int k0 = blockIdx.x * 64, n0 = blockIdx.y * 64;
  int cr = t >> 4, cc = (t & 15) * 4;
#pragma unroll
  for (int p = 0; p < 4; p++) {
    int r = cr + p * 16;
    float4 v = *(const float4*)&w[(size_t)(k0 + r) * 1024 + n0 + cc];
    tile[r][cc + 0] = v.x; tile[r][cc + 1] = v.y; tile[r][cc + 2] = v.z; tile[r][cc + 3] = v.w;
  }
  __syncthreads();
#pragma unroll
  for (int p = 0; p < 4; p++) {
    int nn = cr + p * 16;
    f16x4 h;
    h[0] = (f16)tile[cc + 0][nn]; h[1] = (f16)tile[cc + 1][nn];
    h[2] = (f16)tile[cc + 2][nn]; h[3] = (f16)tile[cc + 3][nn];
    *(f16x4*)&dst[(size_t)(n0 + nn) * 1024 + k0 + cc] = h;
  }
}

// ---------- GEMM core: C[M,N] = A[M,K] @ W^T stored [N,K], fp16 in, fp32 acc ----------
// 128x128 tile, BK=64, 4 waves each 64x64 (4x4 MFMA 16x16x32), XOR-swizzled LDS,
// global_load_lds (16B) staging with pre-swizzled source addresses.
template <bool OUTF32>
__device__ __forceinline__ void gemm_core(const f16* __restrict__ A, const f16* __restrict__ W,
                                          const float* __restrict__ bias,
                                          f16* __restrict__ oh, float* __restrict__ of) {
  __shared__ f16 Al[128 * 64];
  __shared__ f16 Bl[128 * 64];
  const int t = threadIdx.x;
  const int lane = t & 63, wid = t >> 6;
  const int lr = lane & 15, lg = lane >> 4;
  const int m0 = blockIdx.x * 128, n0 = blockIdx.y * 128;
  const int wm = wid >> 1, wn = wid & 1;
  const int lrow = lane >> 3;                       // 0..7 within the wave's 8-row slab
  const int cb = (((lane & 7) ^ lrow) << 4);        // pre-swizzled source byte col

  f32x4 acc[4][4] = {};

  for (int k0 = 0; k0 < 1024; k0 += 64) {
    __syncthreads();
#pragma unroll
    for (int it = 0; it < 4; it++) {
      int rbase = it * 32 + wid * 8;                // wave-uniform
      int row = rbase + lrow;
      gload16((const char*)&A[(size_t)(m0 + row) * 1024 + k0] + cb, (char*)Al + rbase * 128);
      gload16((const char*)&W[(size_t)(n0 + row) * 1024 + k0] + cb, (char*)Bl + rbase * 128);
    }
    __syncthreads();
    f16x8 af[2][4], bf[2][4];
#pragma unroll
    for (int x = 0; x < 4; x++) {
      int ra = wm * 64 + x * 16 + lr;
      int rb = wn * 64 + x * 16 + lr;
#pragma unroll
      for (int kh = 0; kh < 2; kh++) {
        int ca = (kh * 64 + lg * 16) ^ ((lr & 7) << 4);
        af[kh][x] = *(const f16x8*)((char*)Al + ra * 128 + ca);
        bf[kh][x] = *(const f16x8*)((char*)Bl + rb * 128 + ca);
      }
    }
#pragma unroll
    for (int kh = 0; kh < 2; kh++)
#pragma unroll
      for (int mt = 0; mt < 4; mt++)
#pragma unroll
        for (int nt = 0; nt < 4; nt++)
          acc[mt][nt] = MFMA(af[kh][mt], bf[kh][nt], acc[mt][nt]);
  }
#pragma unroll
  for (int mt = 0; mt < 4; mt++) {
#pragma unroll
    for (int nt = 0; nt < 4; nt++) {
      int col = n0 + wn * 64 + nt * 16 + lr;
      float bcol = bias[col];
#pragma unroll
      for (int e = 0; e < 4; e++) {
        int row = m0 + wm * 64 + mt * 16 + lg * 4 + e;
        float val = acc[mt][nt][e] + bcol;
        if (OUTF32) of[(size_t)row * 1024 + col] = val;
        else        oh[(size_t)row * 1024 + col] = (f16)val;
      }
    }
  }
}

__global__ __launch_bounds__(256, 2) void k_gemm_qkv(const f16* __restrict__ A, const f16* __restrict__ wt,
                                                     const float* __restrict__ bq, const float* __restrict__ bk,
                                                     const float* __restrict__ bv,
                                                     f16* __restrict__ q, f16* __restrict__ k, f16* __restrict__ v) {
  int z = blockIdx.z;
  gemm_core<false>(A, wt + (size_t)z * 1024 * 1024,
                   z == 0 ? bq : z == 1 ? bk : bv,
                   z == 0 ? q : z == 1 ? k : v, nullptr);
}

__global__ __launch_bounds__(256, 2) void k_gemm_o(const f16* __restrict__ A, const f16* __restrict__ wt,
                                                   const float* __restrict__ bo, float* __restrict__ out) {
  gemm_core<true>(A, wt, bo, nullptr, out);
}

// ---------- RMSNorm + interleaved RoPE (in-place on fp16 q/k), fp32 math ----------
__global__ __launch_bounds__(256) void k_normrope(f16* __restrict__ qh, f16* __restrict__ kh,
                                                  const float* __restrict__ gq, const float* __restrict__ gk,
                                                  const float* __restrict__ cs, const float* __restrict__ sn) {
  int row = blockIdx.x, which = blockIdx.y;
  f16* buf = which ? kh : qh;
  const float* g = which ? gk : gq;
  int t = threadIdx.x, c4 = t * 4;
  f16x4 xv = *(const f16x4*)&buf[(size_t)row * 1024 + c4];
  float x0 = xv[0], x1 = xv[1], x2 = xv[2], x3 = xv[3];
  float ss = x0 * x0 + x1 * x1 + x2 * x2 + x3 * x3;
#pragma unroll
  for (int off = 1; off < 64; off <<= 1) ss += __shfl_xor(ss, off);
  __shared__ float red[4];
  if ((t & 63) == 0) red[t >> 6] = ss;
  __syncthreads();
  float inv = rsqrtf((red[0] + red[1] + red[2] + red[3]) * (1.0f / 1024.0f) + 1e-6f);
  int tt = row & 2047;
  float4 cv = *(const float4*)&cs[(size_t)tt * 1024 + c4];
  float4 sv = *(const float4*)&sn[(size_t)tt * 1024 + c4];
  float4 gv = *(const float4*)&g[c4];
  float y0 = x0 * inv * gv.x, y1 = x1 * inv * gv.y, y2 = x2 * inv * gv.z, y3 = x3 * inv * gv.w;
  f16x4 ov;
  ov[0] = (f16)(y0 * cv.x - y1 * sv.x);
  ov[1] = (f16)(y1 * cv.y + y0 * sv.y);
  ov[2] = (f16)(y2 * cv.z - y3 * sv.z);
  ov[3] = (f16)(y3 * cv.w + y2 * sv.w);
  *(f16x4*)&buf[(size_t)row * 1024 + c4] = ov;
}

// ---------- V transpose: [b,t,h*64+dh] -> [b,h,dh,t] ----------
__global__ __launch_bounds__(256) void k_vtrans(const f16* __restrict__ vh, f16* __restrict__ vt) {
  __shared__ f16 tile[64][65];
  int t = threadIdx.x;
  int t0 = blockIdx.x * 64;
  int bh = blockIdx.y;
  int b = bh >> 4, h = bh & 15;
  int rr = t >> 3, c8 = (t & 7) * 8;
#pragma unroll
  for (int p = 0; p < 2; p++) {
    int r = p * 32 + rr;
    f16x8 v = *(const f16x8*)&vh[(size_t)(b * 2048 + t0 + r) * 1024 + h * 64 + c8];
#pragma unroll
    for (int j = 0; j < 8; j++) tile[r][c8 + j] = v[j];
  }
  __syncthreads();
#pragma unroll
  for (int p = 0; p < 2; p++) {
    int dh = p * 32 + rr;
    f16x8 o;
#pragma unroll
    for (int j = 0; j < 8; j++) o[j] = tile[c8 + j][dh];
    *(f16x8*)&vt[((size_t)bh * 64 + dh) * 2048 + t0 + c8] = o;
  }
}

// ---------- flash attention v2: swapped QK^T, in-register P, DMA staging ----------
// Per block: 4 waves x 16 q-rows = 64 rows; KV-chunk 64.
// LDS swizzle: byte ^= ((row&3)|((row&8)>>1))<<4  (keeps permuted-key frag reads 2-way).
#define ASWZ(row) ((((row) & 3) | (((row) & 8) >> 1)) << 4)

__global__ __launch_bounds__(256, 4) void k_attn(const f16* __restrict__ qh, const f16* __restrict__ kh,
                                                 const f16* __restrict__ vt, f16* __restrict__ ao) {
  __shared__ f16 Kl[64 * 64];
  __shared__ f16 Vl[64 * 64];
  const int t = threadIdx.x;
  const int lane = t & 63, wid = t >> 6;
  const int lr = lane & 15, lg = lane >> 4;
  const int lgb = lg << 4;
  const int b = blockIdx.y >> 4, h = blockIdx.y & 15;
  const int q0 = blockIdx.x * 64 + wid * 16;
  const f16* Qb = qh + ((size_t)(b * 2048 + q0)) * 1024 + h * 64;
  // Q B-frags: lane holds Q[q0+lr][kh*32 + lg*8 + j]
  f16x8 qf0 = *(const f16x8*)&Qb[(size_t)lr * 1024 + lg * 8];
  f16x8 qf1 = *(const f16x8*)&Qb[(size_t)lr * 1024 + 32 + lg * 8];
  const f16* Kg = kh + ((size_t)b * 2048) * 1024 + h * 64;
  const f16* Vg = vt + ((size_t)blockIdx.y) * 64 * 2048;
  const int lrow = lane >> 3;                 // stage: row within 8-row slab
  const int sg = (lane & 7) << 4;             // stage: dest granule byte
  const float sc = 0.125f * 1.44269504088896340736f;
  float m = -1e30f, l = 0.f;
  f32x4 acc[4] = {};

  for (int kv0 = 0; kv0 < 2048; kv0 += 64) {
    __syncthreads();
#pragma unroll
    for (int i = 0; i < 2; i++) {
      int rbase = (i * 4 + wid) * 8;          // wave-uniform
      int row = rbase + lrow;
      int cswz = sg ^ ASWZ(row);
      gload16((const char*)(Kg + (size_t)(kv0 + row) * 1024) + cswz, (char*)Kl + rbase * 128);
      gload16((const char*)(Vg + (size_t)row * 2048 + kv0) + cswz, (char*)Vl + rbase * 128);
    }
    __syncthreads();

    // S^T = K @ Q^T with permuted key rows so PV A-frags are lane-local.
    f32x4 s[4];
#pragma unroll
    for (int ks = 0; ks < 4; ks++) {
      int key = ((lr >> 2) << 3) + (lr & 3) + ((ks & 1) << 2) + ((ks >> 1) << 5);
      int sw = ASWZ(key);
      f16x8 kf0 = *(const f16x8*)((char*)Kl + key * 128 + (lgb ^ sw));
      f16x8 kf1 = *(const f16x8*)((char*)Kl + key * 128 + ((64 + lgb) ^ sw));
      f32x4 z = {};
      z = MFMA(kf0, qf0, z);
      z = MFMA(kf1, qf1, z);
      s[ks] = z;   // lane holds S[qrow=lr][key = lg*8 + e + (ks&1)*4 + (ks>>1)*32]
    }

    // online softmax: full row in this lane-quad (lanes lr, lr+16, lr+32, lr+48)
    float smax = -1e30f;
#pragma unroll
    for (int ks = 0; ks < 4; ks++)
#pragma unroll
      for (int e = 0; e < 4; e++) smax = fmaxf(smax, s[ks][e]);
    smax = fmaxf(smax, __shfl_xor(smax, 16));
    smax = fmaxf(smax, __shfl_xor(smax, 32));
    float mn = fmaxf(m, smax * sc);
    float al = exp2f(m - mn);
    m = mn;
    float sum = 0.f;
    union { f16x8 v; f16x2 h[4]; } u[2];
#pragma unroll
    for (int ks = 0; ks < 4; ks++) {
      float p0 = exp2f(fmaf(s[ks][0], sc, -mn));
      float p1 = exp2f(fmaf(s[ks][1], sc, -mn));
      float p2 = exp2f(fmaf(s[ks][2], sc, -mn));
      float p3 = exp2f(fmaf(s[ks][3], sc, -mn));
      sum += (p0 + p1) + (p2 + p3);
      u[ks >> 1].h[(ks & 1) * 2 + 0] = PKRTZ(p0, p1);
      u[ks >> 1].h[(ks & 1) * 2 + 1] = PKRTZ(p2, p3);
    }
    sum += __shfl_xor(sum, 16);
    sum += __shfl_xor(sum, 32);
    l = l * al + sum;
    // rescale factors for this lane's acc rows (qrows lg*4+e)
    float alq[4];
#pragma unroll
    for (int e = 0; e < 4; e++) alq[e] = __shfl(al, lg * 4 + e);
#pragma unroll
    for (int ds = 0; ds < 4; ds++)
#pragma unroll
      for (int e = 0; e < 4; e++) acc[ds][e] *= alq[e];

    // PV: A = packed P (in regs), B = V^T LDS rows (contiguous keys)
#pragma unroll
    for (int ds = 0; ds < 4; ds++) {
      int vrow = ds * 16 + lr;
      int sw = ASWZ(vrow);
      f16x8 vf0 = *(const f16x8*)((char*)Vl + vrow * 128 + (lgb ^ sw));
      f16x8 vf1 = *(const f16x8*)((char*)Vl + vrow * 128 + ((64 + lgb) ^ sw));
      acc[ds] = MFMA(u[0].v, vf0, acc[ds]);
      acc[ds] = MFMA(u[1].v, vf1, acc[ds]);
    }
  }

  float lf[4];
#pragma unroll
  for (int e = 0; e < 4; e++) lf[e] = 1.f / __shfl(l, lg * 4 + e);
#pragma unroll
  for (int e = 0; e < 4; e++) {
    size_t row = (size_t)(b * 2048 + q0 + lg * 4 + e);
#pragma unroll
    for (int ds = 0; ds < 4; ds++)
      ao[row * 1024 + h * 64 + ds * 16 + lr] = (f16)(acc[ds][e] * lf[e]);
  }
}

extern "C" void kernel_launch(void* const* d_in, const int* in_sizes, int n_in,
                              void* d_out, int out_size, void* d_ws, size_t ws_size,
                              hipStream_t stream) {
  const float* hid  = (const float*)d_in[0];
  const float* cosb = (const float*)d_in[1];
  const float* sinb = (const float*)d_in[2];
  const float* wq = (const float*)d_in[3];
  const float* bq = (const float*)d_in[4];
  const float* wk = (const float*)d_in[5];
  const float* bk = (const float*)d_in[6];
  const float* wv = (const float*)d_in[7];
  const float* bv = (const float*)d_in[8];
  const float* gq = (const float*)d_in[9];
  const float* gk = (const float*)d_in[10];
  const float* wo = (const float*)d_in[11];
  const float* bo = (const float*)d_in[12];
  float* out = (float*)d_out;

  char* ws = (char*)d_ws;
  f16* aH  = (f16*)(ws);                          // 8 MB: hidden fp16 [4096][1024]
  f16* wt  = (f16*)(ws + ((size_t)8 << 20));      // 8 MB: 4 weights transposed [n][k] fp16
  f16* qh  = (f16*)(ws + ((size_t)16 << 20));     // 8 MB
  f16* khb = (f16*)(ws + ((size_t)24 << 20));     // 8 MB
  f16* vhb = (f16*)(ws + ((size_t)32 << 20));     // 8 MB
  f16* vtb = (f16*)(ws + ((size_t)40 << 20));     // 8 MB: V^T [b,h,dh,t]
  f16* ao  = (f16*)(ws + ((size_t)48 << 20));     // 8 MB: attention out [4096][1024]

  k_cvt_hidden<<<dim3(4096), dim3(256), 0, stream>>>(hid, aH);
  k_cvt_w<<<dim3(16, 16, 4), dim3(256), 0, stream>>>(wq, wk, wv, wo, wt);
  k_gemm_qkv<<<dim3(32, 8, 3), dim3(256), 0, stream>>>(aH, wt, bq, bk, bv, qh, khb, vhb);
  k_normrope<<<dim3(4096, 2), dim3(256), 0, stream>>>(qh, khb, gq, gk, cosb, sinb);
  k_vtrans<<<dim3(32, 32), dim3(256), 0, stream>>>(vhb, vtb);
  k_attn<<<dim3(32, 32), dim3(256), 0, stream>>>(qh, khb, vtb, ao);
  k_gemm_o<<<dim3(32, 8, 1), dim3(256), 0, stream>>>(ao, wt + (size_t)3 * 1024 * 1024, bo, out);
}

// Round 4
// 154.918 us; speedup vs baseline: 1.2996x; 1.0483x over previous
//
#include <hip/hip_runtime.h>

typedef _Float16 f16;
typedef _Float16 f16x8 __attribute__((ext_vector_type(8)));
typedef _Float16 f16x4 __attribute__((ext_vector_type(4)));
typedef _Float16 f16x2 __attribute__((ext_vector_type(2)));
typedef float f32x4 __attribute__((ext_vector_type(4)));

#define MFMA(a, b, c) __builtin_amdgcn_mfma_f32_16x16x32_f16(a, b, c, 0, 0, 0)
#define PKRTZ(a, b) __builtin_bit_cast(f16x2, __builtin_amdgcn_cvt_pkrtz(a, b))

__device__ __forceinline__ void gload16(const void* g, void* l) {
  __builtin_amdgcn_global_load_lds((const __attribute__((address_space(1))) char*)g,
                                   (__attribute__((address_space(3))) char*)l, 16, 0, 0);
}

// B=2, T=2048, D=1024, H=16, DH=64

// ---------- prep: fp32 -> fp16 convert of hidden ----------
__global__ __launch_bounds__(256) void k_cvt_hidden(const float* __restrict__ x, f16* __restrict__ y) {
  int i = blockIdx.x * 256 + threadIdx.x;
  float4 v = ((const float4*)x)[i];
  f16x4 h; h[0] = (f16)v.x; h[1] = (f16)v.y; h[2] = (f16)v.z; h[3] = (f16)v.w;
  ((f16x4*)y)[i] = h;
}

// ---------- prep: transpose+convert weights [k][n] fp32 -> [n][k] fp16 ----------
__global__ __launch_bounds__(256) void k_cvt_w(const float* __restrict__ w0, const float* __restrict__ w1,
                                               const float* __restrict__ w2, const float* __restrict__ w3,
                                               f16* __restrict__ wt) {
  int z = blockIdx.z;
  const float* w = z == 0 ? w0 : z == 1 ? w1 : z == 2 ? w2 : w3;
  f16* dst = wt + (size_t)z * 1024 * 1024;
  __shared__ float tile[64][65];
  int t = threadIdx.x;
  int k0 = blockIdx.x * 64, n0 = blockIdx.y * 64;
  int cr = t >> 4, cc = (t & 15) * 4;
#pragma unroll
  for (int p = 0; p < 4; p++) {
    int r = cr + p * 16;
    float4 v = *(const float4*)&w[(size_t)(k0 + r) * 1024 + n0 + cc];
    tile[r][cc + 0] = v.x; tile[r][cc + 1] = v.y; tile[r][cc + 2] = v.z; tile[r][cc + 3] = v.w;
  }
  __syncthreads();
#pragma unroll
  for (int p = 0; p < 4; p++) {
    int nn = cr + p * 16;
    f16x4 h;
    h[0] = (f16)tile[cc + 0][nn]; h[1] = (f16)tile[cc + 1][nn];
    h[2] = (f16)tile[cc + 2][nn]; h[3] = (f16)tile[cc + 3][nn];
    *(f16x4*)&dst[(size_t)(n0 + nn) * 1024 + k0 + cc] = h;
  }
}

// ---------- GEMM core: C[M,N] = A[M,K] @ W^T stored [N,K], fp16 in, fp32 acc ----------
template <bool OUTF32>
__device__ __forceinline__ void gemm_core(const f16* __restrict__ A, const f16* __restrict__ W,
                                          const float* __restrict__ bias,
                                          f16* __restrict__ oh, float* __restrict__ of) {
  __shared__ f16 Al[128 * 64];
  __shared__ f16 Bl[128 * 64];
  const int t = threadIdx.x;
  const int lane = t & 63, wid = t >> 6;
  const int lr = lane & 15, lg = lane >> 4;
  const int m0 = blockIdx.x * 128, n0 = blockIdx.y * 128;
  const int wm = wid >> 1, wn = wid & 1;
  const int lrow = lane >> 3;                       // 0..7 within the wave's 8-row slab
  const int cb = (((lane & 7) ^ lrow) << 4);        // pre-swizzled source byte col

  f32x4 acc[4][4] = {};

  for (int k0 = 0; k0 < 1024; k0 += 64) {
    __syncthreads();
#pragma unroll
    for (int it = 0; it < 4; it++) {
      int rbase = it * 32 + wid * 8;                // wave-uniform
      int row = rbase + lrow;
      gload16((const char*)&A[(size_t)(m0 + row) * 1024 + k0] + cb, (char*)Al + rbase * 128);
      gload16((const char*)&W[(size_t)(n0 + row) * 1024 + k0] + cb, (char*)Bl + rbase * 128);
    }
    __syncthreads();
    f16x8 af[2][4], bf[2][4];
#pragma unroll
    for (int x = 0; x < 4; x++) {
      int ra = wm * 64 + x * 16 + lr;
      int rb = wn * 64 + x * 16 + lr;
#pragma unroll
      for (int kh = 0; kh < 2; kh++) {
        int ca = (kh * 64 + lg * 16) ^ ((lr & 7) << 4);
        af[kh][x] = *(const f16x8*)((char*)Al + ra * 128 + ca);
        bf[kh][x] = *(const f16x8*)((char*)Bl + rb * 128 + ca);
      }
    }
#pragma unroll
    for (int kh = 0; kh < 2; kh++)
#pragma unroll
      for (int mt = 0; mt < 4; mt++)
#pragma unroll
        for (int nt = 0; nt < 4; nt++)
          acc[mt][nt] = MFMA(af[kh][mt], bf[kh][nt], acc[mt][nt]);
  }
#pragma unroll
  for (int mt = 0; mt < 4; mt++) {
#pragma unroll
    for (int nt = 0; nt < 4; nt++) {
      int col = n0 + wn * 64 + nt * 16 + lr;
      float bcol = bias[col];
#pragma unroll
      for (int e = 0; e < 4; e++) {
        int row = m0 + wm * 64 + mt * 16 + lg * 4 + e;
        float val = acc[mt][nt][e] + bcol;
        if (OUTF32) of[(size_t)row * 1024 + col] = val;
        else        oh[(size_t)row * 1024 + col] = (f16)val;
      }
    }
  }
}

__global__ __launch_bounds__(256, 2) void k_gemm_qkv(const f16* __restrict__ A, const f16* __restrict__ wt,
                                                     const float* __restrict__ bq, const float* __restrict__ bk,
                                                     const float* __restrict__ bv,
                                                     f16* __restrict__ q, f16* __restrict__ k, f16* __restrict__ v) {
  int z = blockIdx.z;
  gemm_core<false>(A, wt + (size_t)z * 1024 * 1024,
                   z == 0 ? bq : z == 1 ? bk : bv,
                   z == 0 ? q : z == 1 ? k : v, nullptr);
}

__global__ __launch_bounds__(256, 2) void k_gemm_o(const f16* __restrict__ A, const f16* __restrict__ wt,
                                                   const float* __restrict__ bo, float* __restrict__ out) {
  gemm_core<true>(A, wt, bo, nullptr, out);
}

// ---------- RMSNorm + interleaved RoPE (in-place on fp16 q/k), fp32 math ----------
__global__ __launch_bounds__(256) void k_normrope(f16* __restrict__ qh, f16* __restrict__ kh,
                                                  const float* __restrict__ gq, const float* __restrict__ gk,
                                                  const float* __restrict__ cs, const float* __restrict__ sn) {
  int row = blockIdx.x, which = blockIdx.y;
  f16* buf = which ? kh : qh;
  const float* g = which ? gk : gq;
  int t = threadIdx.x, c4 = t * 4;
  f16x4 xv = *(const f16x4*)&buf[(size_t)row * 1024 + c4];
  float x0 = xv[0], x1 = xv[1], x2 = xv[2], x3 = xv[3];
  float ss = x0 * x0 + x1 * x1 + x2 * x2 + x3 * x3;
#pragma unroll
  for (int off = 1; off < 64; off <<= 1) ss += __shfl_xor(ss, off);
  __shared__ float red[4];
  if ((t & 63) == 0) red[t >> 6] = ss;
  __syncthreads();
  float inv = rsqrtf((red[0] + red[1] + red[2] + red[3]) * (1.0f / 1024.0f) + 1e-6f);
  int tt = row & 2047;
  float4 cv = *(const float4*)&cs[(size_t)tt * 1024 + c4];
  float4 sv = *(const float4*)&sn[(size_t)tt * 1024 + c4];
  float4 gv = *(const float4*)&g[c4];
  float y0 = x0 * inv * gv.x, y1 = x1 * inv * gv.y, y2 = x2 * inv * gv.z, y3 = x3 * inv * gv.w;
  f16x4 ov;
  ov[0] = (f16)(y0 * cv.x - y1 * sv.x);
  ov[1] = (f16)(y1 * cv.y + y0 * sv.y);
  ov[2] = (f16)(y2 * cv.z - y3 * sv.z);
  ov[3] = (f16)(y3 * cv.w + y2 * sv.w);
  *(f16x4*)&buf[(size_t)row * 1024 + c4] = ov;
}

// ---------- V transpose: [b,t,h*64+dh] -> [b,h,dh,t] ----------
__global__ __launch_bounds__(256) void k_vtrans(const f16* __restrict__ vh, f16* __restrict__ vt) {
  __shared__ f16 tile[64][65];
  int t = threadIdx.x;
  int t0 = blockIdx.x * 64;
  int bh = blockIdx.y;
  int b = bh >> 4, h = bh & 15;
  int rr = t >> 3, c8 = (t & 7) * 8;
#pragma unroll
  for (int p = 0; p < 2; p++) {
    int r = p * 32 + rr;
    f16x8 v = *(const f16x8*)&vh[(size_t)(b * 2048 + t0 + r) * 1024 + h * 64 + c8];
#pragma unroll
    for (int j = 0; j < 8; j++) tile[r][c8 + j] = v[j];
  }
  __syncthreads();
#pragma unroll
  for (int p = 0; p < 2; p++) {
    int dh = p * 32 + rr;
    f16x8 o;
#pragma unroll
    for (int j = 0; j < 8; j++) o[j] = tile[c8 + j][dh];
    *(f16x8*)&vt[((size_t)bh * 64 + dh) * 2048 + t0 + c8] = o;
  }
}

// ---------- flash attention v3: double-buffered single-barrier pipeline ----------
// Per block: 4 waves x 16 q-rows = 64 rows; KV-chunk 64; K/V LDS double-buffered.
// Per chunk: stage(next -> buf^1) || compute(buf) ; one barrier. Defer-max (THR=8).
#define ASWZ(row) ((((row) & 3) | (((row) & 8) >> 1)) << 4)

__global__ __launch_bounds__(256, 4) void k_attn(const f16* __restrict__ qh, const f16* __restrict__ kh,
                                                 const f16* __restrict__ vt, f16* __restrict__ ao) {
  __shared__ f16 Kl[2][64 * 64];
  __shared__ f16 Vl[2][64 * 64];
  const int t = threadIdx.x;
  const int lane = t & 63, wid = t >> 6;
  const int lr = lane & 15, lg = lane >> 4;
  const int lgb = lg << 4;
  // XCD-aware remap: each XCD (raw%8) owns 4 consecutive bh groups -> KV fits its L2.
  const int raw = blockIdx.y * 32 + blockIdx.x;
  const int mybh = ((raw & 7) << 2) | ((raw >> 3) & 3);
  const int myq = raw >> 5;
  const int b = mybh >> 4, h = mybh & 15;
  const int q0 = myq * 64 + wid * 16;
  const f16* Qb = qh + ((size_t)(b * 2048 + q0)) * 1024 + h * 64;
  f16x8 qf0 = *(const f16x8*)&Qb[(size_t)lr * 1024 + lg * 8];
  f16x8 qf1 = *(const f16x8*)&Qb[(size_t)lr * 1024 + 32 + lg * 8];
  const f16* Kg = kh + ((size_t)b * 2048) * 1024 + h * 64;
  const f16* Vg = vt + ((size_t)mybh) * 64 * 2048;
  const int lrow = lane >> 3;
  const int sg = (lane & 7) << 4;
  const float sc = 0.125f * 1.44269504088896340736f;
  float m = -1e30f, l = 0.f;
  f32x4 acc[4] = {};

  auto stage = [&](int kvo, int bs) {
#pragma unroll
    for (int i = 0; i < 2; i++) {
      int rbase = (i * 4 + wid) * 8;          // wave-uniform
      int row = rbase + lrow;
      int cswz = sg ^ ASWZ(row);
      gload16((const char*)(Kg + (size_t)(kvo + row) * 1024) + cswz, (char*)&Kl[bs][0] + rbase * 128);
      gload16((const char*)(Vg + (size_t)row * 2048 + kvo) + cswz, (char*)&Vl[bs][0] + rbase * 128);
    }
  };

  stage(0, 0);
  __syncthreads();
  int cur = 0;

  for (int kv0 = 0; kv0 < 2048; kv0 += 64) {
    if (kv0 + 64 < 2048) stage(kv0 + 64, cur ^ 1);
    const char* Kb = (const char*)&Kl[cur][0];
    const char* Vb = (const char*)&Vl[cur][0];

    // S^T = K @ Q^T with permuted key rows so PV A-frags are lane-local.
    f32x4 s[4];
#pragma unroll
    for (int ks = 0; ks < 4; ks++) {
      int key = ((lr >> 2) << 3) + (lr & 3) + ((ks & 1) << 2) + ((ks >> 1) << 5);
      int sw = ASWZ(key);
      f16x8 kf0 = *(const f16x8*)(Kb + key * 128 + (lgb ^ sw));
      f16x8 kf1 = *(const f16x8*)(Kb + key * 128 + ((64 + lgb) ^ sw));
      f32x4 z = {};
      z = MFMA(kf0, qf0, z);
      z = MFMA(kf1, qf1, z);
      s[ks] = z;   // lane holds S[qrow=lr][key = lg*8 + e + (ks&1)*4 + (ks>>1)*32]
    }

    // row max via max3 chains (full row lives in lane-quad {lr,+16,+32,+48})
    float smax = fmaxf(fmaxf(s[0][0], s[0][1]), s[0][2]);
    smax = fmaxf(fmaxf(smax, s[0][3]), s[1][0]);
    smax = fmaxf(fmaxf(smax, s[1][1]), s[1][2]);
    smax = fmaxf(fmaxf(smax, s[1][3]), s[2][0]);
    smax = fmaxf(fmaxf(smax, s[2][1]), s[2][2]);
    smax = fmaxf(fmaxf(smax, s[2][3]), s[3][0]);
    smax = fmaxf(fmaxf(smax, s[3][1]), s[3][2]);
    smax = fmaxf(smax, s[3][3]);
    smax = fmaxf(smax, __shfl_xor(smax, 16));
    smax = fmaxf(smax, __shfl_xor(smax, 32));
    float smc = smax * sc;

    // defer-max: only rescale when the max grew by >8 (exp2 domain)
    if (!__all(smc - m <= 8.f)) {
      float mn = fmaxf(m, smc);
      float al = exp2f(m - mn);
      m = mn;
      float alq[4];
#pragma unroll
      for (int e = 0; e < 4; e++) alq[e] = __shfl(al, lg * 4 + e);
      l *= al;
#pragma unroll
      for (int ds = 0; ds < 4; ds++)
#pragma unroll
        for (int e = 0; e < 4; e++) acc[ds][e] *= alq[e];
    }

    float sum = 0.f;
    union { f16x8 v; f16x2 h[4]; } u[2];
#pragma unroll
    for (int ks = 0; ks < 4; ks++) {
      float p0 = exp2f(fmaf(s[ks][0], sc, -m));
      float p1 = exp2f(fmaf(s[ks][1], sc, -m));
      float p2 = exp2f(fmaf(s[ks][2], sc, -m));
      float p3 = exp2f(fmaf(s[ks][3], sc, -m));
      sum += (p0 + p1) + (p2 + p3);
      u[ks >> 1].h[(ks & 1) * 2 + 0] = PKRTZ(p0, p1);
      u[ks >> 1].h[(ks & 1) * 2 + 1] = PKRTZ(p2, p3);
    }
    sum += __shfl_xor(sum, 16);
    sum += __shfl_xor(sum, 32);
    l += sum;

    // PV: A = packed P (in regs), B = V^T LDS rows (contiguous keys)
#pragma unroll
    for (int ds = 0; ds < 4; ds++) {
      int vrow = ds * 16 + lr;
      int sw = ASWZ(vrow);
      f16x8 vf0 = *(const f16x8*)(Vb + vrow * 128 + (lgb ^ sw));
      f16x8 vf1 = *(const f16x8*)(Vb + vrow * 128 + ((64 + lgb) ^ sw));
      acc[ds] = MFMA(u[0].v, vf0, acc[ds]);
      acc[ds] = MFMA(u[1].v, vf1, acc[ds]);
    }

    __syncthreads();   // drains stage loads (vmcnt) + protects LDS reuse
    cur ^= 1;
  }

  float lf[4];
#pragma unroll
  for (int e = 0; e < 4; e++) lf[e] = 1.f / __shfl(l, lg * 4 + e);
#pragma unroll
  for (int e = 0; e < 4; e++) {
    size_t row = (size_t)(b * 2048 + q0 + lg * 4 + e);
#pragma unroll
    for (int ds = 0; ds < 4; ds++)
      ao[row * 1024 + h * 64 + ds * 16 + lr] = (f16)(acc[ds][e] * lf[e]);
  }
}

extern "C" void kernel_launch(void* const* d_in, const int* in_sizes, int n_in,
                              void* d_out, int out_size, void* d_ws, size_t ws_size,
                              hipStream_t stream) {
  const float* hid  = (const float*)d_in[0];
  const float* cosb = (const float*)d_in[1];
  const float* sinb = (const float*)d_in[2];
  const float* wq = (const float*)d_in[3];
  const float* bq = (const float*)d_in[4];
  const float* wk = (const float*)d_in[5];
  const float* bk = (const float*)d_in[6];
  const float* wv = (const float*)d_in[7];
  const float* bv = (const float*)d_in[8];
  const float* gq = (const float*)d_in[9];
  const float* gk = (const float*)d_in[10];
  const float* wo = (const float*)d_in[11];
  const float* bo = (const float*)d_in[12];
  float* out = (float*)d_out;

  char* ws = (char*)d_ws;
  f16* aH  = (f16*)(ws);                          // 8 MB: hidden fp16 [4096][1024]
  f16* wt  = (f16*)(ws + ((size_t)8 << 20));      // 8 MB: 4 weights transposed [n][k] fp16
  f16* qh  = (f16*)(ws + ((size_t)16 << 20));     // 8 MB
  f16* khb = (f16*)(ws + ((size_t)24 << 20));     // 8 MB
  f16* vhb = (f16*)(ws + ((size_t)32 << 20));     // 8 MB
  f16* vtb = (f16*)(ws + ((size_t)40 << 20));     // 8 MB: V^T [b,h,dh,t]
  f16* ao  = (f16*)(ws + ((size_t)48 << 20));     // 8 MB: attention out [4096][1024]

  k_cvt_hidden<<<dim3(4096), dim3(256), 0, stream>>>(hid, aH);
  k_cvt_w<<<dim3(16, 16, 4), dim3(256), 0, stream>>>(wq, wk, wv, wo, wt);
  k_gemm_qkv<<<dim3(32, 8, 3), dim3(256), 0, stream>>>(aH, wt, bq, bk, bv, qh, khb, vhb);
  k_normrope<<<dim3(4096, 2), dim3(256), 0, stream>>>(qh, khb, gq, gk, cosb, sinb);
  k_vtrans<<<dim3(32, 32), dim3(256), 0, stream>>>(vhb, vtb);
  k_attn<<<dim3(32, 32), dim3(256), 0, stream>>>(qh, khb, vtb, ao);
  k_gemm_o<<<dim3(32, 8, 1), dim3(256), 0, stream>>>(ao, wt + (size_t)3 * 1024 * 1024, bo, out);
}

// Round 5
// 151.037 us; speedup vs baseline: 1.3330x; 1.0257x over previous
//
#include <hip/hip_runtime.h>

typedef _Float16 f16;
typedef _Float16 f16x8 __attribute__((ext_vector_type(8)));
typedef _Float16 f16x4 __attribute__((ext_vector_type(4)));
typedef _Float16 f16x2 __attribute__((ext_vector_type(2)));
typedef float f32x4 __attribute__((ext_vector_type(4)));

#define MFMA(a, b, c) __builtin_amdgcn_mfma_f32_16x16x32_f16(a, b, c, 0, 0, 0)
#define PKRTZ(a, b) __builtin_bit_cast(f16x2, __builtin_amdgcn_cvt_pkrtz(a, b))

__device__ __forceinline__ void gload16(const void* g, void* l) {
  __builtin_amdgcn_global_load_lds((const __attribute__((address_space(1))) char*)g,
                                   (__attribute__((address_space(3))) char*)l, 16, 0, 0);
}

// B=2, T=2048, D=1024, H=16, DH=64

// ---------- prep: fp32 -> fp16 convert of hidden ----------
__global__ __launch_bounds__(256) void k_cvt_hidden(const float* __restrict__ x, f16* __restrict__ y) {
  int i = blockIdx.x * 256 + threadIdx.x;
  float4 v = ((const float4*)x)[i];
  f16x4 h; h[0] = (f16)v.x; h[1] = (f16)v.y; h[2] = (f16)v.z; h[3] = (f16)v.w;
  ((f16x4*)y)[i] = h;
}

// ---------- prep: transpose+convert weights [k][n] fp32 -> [n][k] fp16 ----------
__global__ __launch_bounds__(256) void k_cvt_w(const float* __restrict__ w0, const float* __restrict__ w1,
                                               const float* __restrict__ w2, const float* __restrict__ w3,
                                               f16* __restrict__ wt) {
  int z = blockIdx.z;
  const float* w = z == 0 ? w0 : z == 1 ? w1 : z == 2 ? w2 : w3;
  f16* dst = wt + (size_t)z * 1024 * 1024;
  __shared__ float tile[64][65];
  int t = threadIdx.x;
  int k0 = blockIdx.x * 64, n0 = blockIdx.y * 64;
  int cr = t >> 4, cc = (t & 15) * 4;
#pragma unroll
  for (int p = 0; p < 4; p++) {
    int r = cr + p * 16;
    float4 v = *(const float4*)&w[(size_t)(k0 + r) * 1024 + n0 + cc];
    tile[r][cc + 0] = v.x; tile[r][cc + 1] = v.y; tile[r][cc + 2] = v.z; tile[r][cc + 3] = v.w;
  }
  __syncthreads();
#pragma unroll
  for (int p = 0; p < 4; p++) {
    int nn = cr + p * 16;
    f16x4 h;
    h[0] = (f16)tile[cc + 0][nn]; h[1] = (f16)tile[cc + 1][nn];
    h[2] = (f16)tile[cc + 2][nn]; h[3] = (f16)tile[cc + 3][nn];
    *(f16x4*)&dst[(size_t)(n0 + nn) * 1024 + k0 + cc] = h;
  }
}

// ---------- GEMM core: C[M,N] = A[M,K] @ W^T stored [N,K], fp16 in, fp32 acc ----------
// 128x128 tile, BK=64, double-buffered LDS, single barrier per K-step.
template <bool OUTF32>
__device__ __forceinline__ void gemm_core(const f16* __restrict__ A, const f16* __restrict__ W,
                                          const float* __restrict__ bias,
                                          f16* __restrict__ oh, float* __restrict__ of) {
  __shared__ f16 Al[2][128 * 64];
  __shared__ f16 Bl[2][128 * 64];
  const int t = threadIdx.x;
  const int lane = t & 63, wid = t >> 6;
  const int lr = lane & 15, lg = lane >> 4;
  const int m0 = blockIdx.x * 128, n0 = blockIdx.y * 128;
  const int wm = wid >> 1, wn = wid & 1;
  const int lrow = lane >> 3;                       // 0..7 within the wave's 8-row slab
  const int cb = (((lane & 7) ^ lrow) << 4);        // pre-swizzled source byte col

  f32x4 acc[4][4] = {};

  auto stage = [&](int k0, int bs) {
#pragma unroll
    for (int it = 0; it < 4; it++) {
      int rbase = it * 32 + wid * 8;                // wave-uniform
      int row = rbase + lrow;
      gload16((const char*)&A[(size_t)(m0 + row) * 1024 + k0] + cb, (char*)&Al[bs][0] + rbase * 128);
      gload16((const char*)&W[(size_t)(n0 + row) * 1024 + k0] + cb, (char*)&Bl[bs][0] + rbase * 128);
    }
  };

  stage(0, 0);
  __syncthreads();
  int cur = 0;
  for (int k0 = 0; k0 < 1024; k0 += 64) {
    if (k0 + 64 < 1024) stage(k0 + 64, cur ^ 1);
    f16x8 af[2][4], bf[2][4];
#pragma unroll
    for (int x = 0; x < 4; x++) {
      int ra = wm * 64 + x * 16 + lr;
      int rb = wn * 64 + x * 16 + lr;
#pragma unroll
      for (int kh = 0; kh < 2; kh++) {
        int ca = (kh * 64 + lg * 16) ^ ((lr & 7) << 4);
        af[kh][x] = *(const f16x8*)((char*)&Al[cur][0] + ra * 128 + ca);
        bf[kh][x] = *(const f16x8*)((char*)&Bl[cur][0] + rb * 128 + ca);
      }
    }
#pragma unroll
    for (int kh = 0; kh < 2; kh++)
#pragma unroll
      for (int mt = 0; mt < 4; mt++)
#pragma unroll
        for (int nt = 0; nt < 4; nt++)
          acc[mt][nt] = MFMA(af[kh][mt], bf[kh][nt], acc[mt][nt]);
    __syncthreads();
    cur ^= 1;
  }
#pragma unroll
  for (int mt = 0; mt < 4; mt++) {
#pragma unroll
    for (int nt = 0; nt < 4; nt++) {
      int col = n0 + wn * 64 + nt * 16 + lr;
      float bcol = bias[col];
#pragma unroll
      for (int e = 0; e < 4; e++) {
        int row = m0 + wm * 64 + mt * 16 + lg * 4 + e;
        float val = acc[mt][nt][e] + bcol;
        if (OUTF32) of[(size_t)row * 1024 + col] = val;
        else        oh[(size_t)row * 1024 + col] = (f16)val;
      }
    }
  }
}

__global__ __launch_bounds__(256, 2) void k_gemm_qkv(const f16* __restrict__ A, const f16* __restrict__ wt,
                                                     const float* __restrict__ bq, const float* __restrict__ bk,
                                                     const float* __restrict__ bv,
                                                     f16* __restrict__ q, f16* __restrict__ k, f16* __restrict__ v) {
  int z = blockIdx.z;
  gemm_core<false>(A, wt + (size_t)z * 1024 * 1024,
                   z == 0 ? bq : z == 1 ? bk : bv,
                   z == 0 ? q : z == 1 ? k : v, nullptr);
}

__global__ __launch_bounds__(256, 2) void k_gemm_o(const f16* __restrict__ A, const f16* __restrict__ wt,
                                                   const float* __restrict__ bo, float* __restrict__ out) {
  gemm_core<true>(A, wt, bo, nullptr, out);
}

// ---------- RMSNorm + interleaved RoPE (in-place on fp16 q/k), fp32 math ----------
__global__ __launch_bounds__(256) void k_normrope(f16* __restrict__ qh, f16* __restrict__ kh,
                                                  const float* __restrict__ gq, const float* __restrict__ gk,
                                                  const float* __restrict__ cs, const float* __restrict__ sn) {
  int row = blockIdx.x, which = blockIdx.y;
  f16* buf = which ? kh : qh;
  const float* g = which ? gk : gq;
  int t = threadIdx.x, c4 = t * 4;
  f16x4 xv = *(const f16x4*)&buf[(size_t)row * 1024 + c4];
  float x0 = xv[0], x1 = xv[1], x2 = xv[2], x3 = xv[3];
  float ss = x0 * x0 + x1 * x1 + x2 * x2 + x3 * x3;
#pragma unroll
  for (int off = 1; off < 64; off <<= 1) ss += __shfl_xor(ss, off);
  __shared__ float red[4];
  if ((t & 63) == 0) red[t >> 6] = ss;
  __syncthreads();
  float inv = rsqrtf((red[0] + red[1] + red[2] + red[3]) * (1.0f / 1024.0f) + 1e-6f);
  int tt = row & 2047;
  float4 cv = *(const float4*)&cs[(size_t)tt * 1024 + c4];
  float4 sv = *(const float4*)&sn[(size_t)tt * 1024 + c4];
  float4 gv = *(const float4*)&g[c4];
  float y0 = x0 * inv * gv.x, y1 = x1 * inv * gv.y, y2 = x2 * inv * gv.z, y3 = x3 * inv * gv.w;
  f16x4 ov;
  ov[0] = (f16)(y0 * cv.x - y1 * sv.x);
  ov[1] = (f16)(y1 * cv.y + y0 * sv.y);
  ov[2] = (f16)(y2 * cv.z - y3 * sv.z);
  ov[3] = (f16)(y3 * cv.w + y2 * sv.w);
  *(f16x4*)&buf[(size_t)row * 1024 + c4] = ov;
}

// ---------- V transpose: [b,t,h*64+dh] -> [b,h,dh,t] ----------
__global__ __launch_bounds__(256) void k_vtrans(const f16* __restrict__ vh, f16* __restrict__ vt) {
  __shared__ f16 tile[64][65];
  int t = threadIdx.x;
  int t0 = blockIdx.x * 64;
  int bh = blockIdx.y;
  int b = bh >> 4, h = bh & 15;
  int rr = t >> 3, c8 = (t & 7) * 8;
#pragma unroll
  for (int p = 0; p < 2; p++) {
    int r = p * 32 + rr;
    f16x8 v = *(const f16x8*)&vh[(size_t)(b * 2048 + t0 + r) * 1024 + h * 64 + c8];
#pragma unroll
    for (int j = 0; j < 8; j++) tile[r][c8 + j] = v[j];
  }
  __syncthreads();
#pragma unroll
  for (int p = 0; p < 2; p++) {
    int dh = p * 32 + rr;
    f16x8 o;
#pragma unroll
    for (int j = 0; j < 8; j++) o[j] = tile[c8 + j][dh];
    *(f16x8*)&vt[((size_t)bh * 64 + dh) * 2048 + t0 + c8] = o;
  }
}

// ---------- flash attention v4: cross-chunk pipelined QK^T ----------
// Per iter: QK(i+1) MFMAs issue FIRST, then softmax(i)+PV(i) on last iter's scores
// run while they complete. K/V double-buffered; one barrier per chunk. Defer-max.
#define ASWZ(row) ((((row) & 3) | (((row) & 8) >> 1)) << 4)

__global__ __launch_bounds__(256, 4) void k_attn(const f16* __restrict__ qh, const f16* __restrict__ kh,
                                                 const f16* __restrict__ vt, f16* __restrict__ ao) {
  __shared__ f16 Kl[2][64 * 64];
  __shared__ f16 Vl[2][64 * 64];
  const int t = threadIdx.x;
  const int lane = t & 63, wid = t >> 6;
  const int lr = lane & 15, lg = lane >> 4;
  const int lgb = lg << 4;
  // XCD-aware remap: each XCD (raw%8) owns 4 consecutive bh groups -> KV fits its L2.
  const int raw = blockIdx.y * 32 + blockIdx.x;
  const int mybh = ((raw & 7) << 2) | ((raw >> 3) & 3);
  const int myq = raw >> 5;
  const int b = mybh >> 4, h = mybh & 15;
  const int q0 = myq * 64 + wid * 16;
  const f16* Qb = qh + ((size_t)(b * 2048 + q0)) * 1024 + h * 64;
  f16x8 qf0 = *(const f16x8*)&Qb[(size_t)lr * 1024 + lg * 8];
  f16x8 qf1 = *(const f16x8*)&Qb[(size_t)lr * 1024 + 32 + lg * 8];
  const f16* Kg = kh + ((size_t)b * 2048) * 1024 + h * 64;
  const f16* Vg = vt + ((size_t)mybh) * 64 * 2048;
  const int lrow = lane >> 3;
  const int sg = (lane & 7) << 4;
  const float sc = 0.125f * 1.44269504088896340736f;
  float m = -1e30f, l = 0.f;
  f32x4 acc[4] = {};

  auto stageK = [&](int kvo, int bs) {
#pragma unroll
    for (int i = 0; i < 2; i++) {
      int rbase = (i * 4 + wid) * 8;          // wave-uniform
      int row = rbase + lrow;
      int cswz = sg ^ ASWZ(row);
      gload16((const char*)(Kg + (size_t)(kvo + row) * 1024) + cswz, (char*)&Kl[bs][0] + rbase * 128);
    }
  };
  auto stageV = [&](int kvo, int bs) {
#pragma unroll
    for (int i = 0; i < 2; i++) {
      int rbase = (i * 4 + wid) * 8;
      int row = rbase + lrow;
      int cswz = sg ^ ASWZ(row);
      gload16((const char*)(Vg + (size_t)row * 2048 + kvo) + cswz, (char*)&Vl[bs][0] + rbase * 128);
    }
  };

  // S^T = K @ Q^T with permuted key rows so PV A-frags are lane-local.
  auto qkt = [&](int bs, f32x4* s) {
    const char* Kb = (const char*)&Kl[bs][0];
    __builtin_amdgcn_s_setprio(1);
#pragma unroll
    for (int ks = 0; ks < 4; ks++) {
      int key = ((lr >> 2) << 3) + (lr & 3) + ((ks & 1) << 2) + ((ks >> 1) << 5);
      int sw = ASWZ(key);
      f16x8 kf0 = *(const f16x8*)(Kb + key * 128 + (lgb ^ sw));
      f16x8 kf1 = *(const f16x8*)(Kb + key * 128 + ((64 + lgb) ^ sw));
      f32x4 z = {};
      z = MFMA(kf0, qf0, z);
      z = MFMA(kf1, qf1, z);
      s[ks] = z;   // lane holds S[qrow=lr][key = lg*8 + e + (ks&1)*4 + (ks>>1)*32]
    }
    __builtin_amdgcn_s_setprio(0);
  };

  // softmax + PV on scores s, V buffer vb
  auto finish = [&](f32x4* s, int vb) {
    float smax = fmaxf(fmaxf(s[0][0], s[0][1]), s[0][2]);
    smax = fmaxf(fmaxf(smax, s[0][3]), s[1][0]);
    smax = fmaxf(fmaxf(smax, s[1][1]), s[1][2]);
    smax = fmaxf(fmaxf(smax, s[1][3]), s[2][0]);
    smax = fmaxf(fmaxf(smax, s[2][1]), s[2][2]);
    smax = fmaxf(fmaxf(smax, s[2][3]), s[3][0]);
    smax = fmaxf(fmaxf(smax, s[3][1]), s[3][2]);
    smax = fmaxf(smax, s[3][3]);
    smax = fmaxf(smax, __shfl_xor(smax, 16));
    smax = fmaxf(smax, __shfl_xor(smax, 32));
    float smc = smax * sc;

    if (!__all(smc - m <= 8.f)) {          // defer-max: rescale only on real growth
      float mn = fmaxf(m, smc);
      float al = exp2f(m - mn);
      m = mn;
      float alq[4];
#pragma unroll
      for (int e = 0; e < 4; e++) alq[e] = __shfl(al, lg * 4 + e);
      l *= al;
#pragma unroll
      for (int ds = 0; ds < 4; ds++)
#pragma unroll
        for (int e = 0; e < 4; e++) acc[ds][e] *= alq[e];
    }

    float sum = 0.f;
    union { f16x8 v; f16x2 h[4]; } u[2];
#pragma unroll
    for (int ks = 0; ks < 4; ks++) {
      float p0 = exp2f(fmaf(s[ks][0], sc, -m));
      float p1 = exp2f(fmaf(s[ks][1], sc, -m));
      float p2 = exp2f(fmaf(s[ks][2], sc, -m));
      float p3 = exp2f(fmaf(s[ks][3], sc, -m));
      sum += (p0 + p1) + (p2 + p3);
      u[ks >> 1].h[(ks & 1) * 2 + 0] = PKRTZ(p0, p1);
      u[ks >> 1].h[(ks & 1) * 2 + 1] = PKRTZ(p2, p3);
    }
    sum += __shfl_xor(sum, 16);
    sum += __shfl_xor(sum, 32);
    l += sum;

    const char* Vb = (const char*)&Vl[vb][0];
    __builtin_amdgcn_s_setprio(1);
#pragma unroll
    for (int ds = 0; ds < 4; ds++) {
      int vrow = ds * 16 + lr;
      int sw = ASWZ(vrow);
      f16x8 vf0 = *(const f16x8*)(Vb + vrow * 128 + (lgb ^ sw));
      f16x8 vf1 = *(const f16x8*)(Vb + vrow * 128 + ((64 + lgb) ^ sw));
      acc[ds] = MFMA(u[0].v, vf0, acc[ds]);
      acc[ds] = MFMA(u[1].v, vf1, acc[ds]);
    }
    __builtin_amdgcn_s_setprio(0);
  };

  f32x4 sA[4], sB[4];
  // prologue: chunk0 resident, S(0) computed, K(1) staged+drained
  stageK(0, 0); stageV(0, 0);
  __syncthreads();
  qkt(0, sA);
  stageK(64, 1);
  __syncthreads();

  for (int i = 0; i < 32; i += 2) {
    // ---- iter i (even): consume sA, QK(i+1)->sB ----
    qkt(1, sB);                                   // K(i+1) in Kl[1]
    if (i + 2 < 32) stageK((i + 2) * 64, 0);      // K(i) dead
    stageV((i + 1) * 64, 1);
    finish(sA, 0);                                // softmax(i) + PV from Vl[0]
    __syncthreads();
    // ---- iter i+1 (odd): consume sB, QK(i+2)->sA ----
    if (i + 2 < 32) qkt(0, sA);
    if (i + 3 < 32) stageK((i + 3) * 64, 1);
    if (i + 2 < 32) stageV((i + 2) * 64, 0);
    finish(sB, 1);                                // softmax(i+1) + PV from Vl[1]
    __syncthreads();
  }

  float lf[4];
#pragma unroll
  for (int e = 0; e < 4; e++) lf[e] = 1.f / __shfl(l, lg * 4 + e);
#pragma unroll
  for (int e = 0; e < 4; e++) {
    size_t row = (size_t)(b * 2048 + q0 + lg * 4 + e);
#pragma unroll
    for (int ds = 0; ds < 4; ds++)
      ao[row * 1024 + h * 64 + ds * 16 + lr] = (f16)(acc[ds][e] * lf[e]);
  }
}

extern "C" void kernel_launch(void* const* d_in, const int* in_sizes, int n_in,
                              void* d_out, int out_size, void* d_ws, size_t ws_size,
                              hipStream_t stream) {
  const float* hid  = (const float*)d_in[0];
  const float* cosb = (const float*)d_in[1];
  const float* sinb = (const float*)d_in[2];
  const float* wq = (const float*)d_in[3];
  const float* bq = (const float*)d_in[4];
  const float* wk = (const float*)d_in[5];
  const float* bk = (const float*)d_in[6];
  const float* wv = (const float*)d_in[7];
  const float* bv = (const float*)d_in[8];
  const float* gq = (const float*)d_in[9];
  const float* gk = (const float*)d_in[10];
  const float* wo = (const float*)d_in[11];
  const float* bo = (const float*)d_in[12];
  float* out = (float*)d_out;

  char* ws = (char*)d_ws;
  f16* aH  = (f16*)(ws);                          // 8 MB: hidden fp16 [4096][1024]
  f16* wt  = (f16*)(ws + ((size_t)8 << 20));      // 8 MB: 4 weights transposed [n][k] fp16
  f16* qh  = (f16*)(ws + ((size_t)16 << 20));     // 8 MB
  f16* khb = (f16*)(ws + ((size_t)24 << 20));     // 8 MB
  f16* vhb = (f16*)(ws + ((size_t)32 << 20));     // 8 MB
  f16* vtb = (f16*)(ws + ((size_t)40 << 20));     // 8 MB: V^T [b,h,dh,t]
  f16* ao  = (f16*)(ws + ((size_t)48 << 20));     // 8 MB: attention out [4096][1024]

  k_cvt_hidden<<<dim3(4096), dim3(256), 0, stream>>>(hid, aH);
  k_cvt_w<<<dim3(16, 16, 4), dim3(256), 0, stream>>>(wq, wk, wv, wo, wt);
  k_gemm_qkv<<<dim3(32, 8, 3), dim3(256), 0, stream>>>(aH, wt, bq, bk, bv, qh, khb, vhb);
  k_normrope<<<dim3(4096, 2), dim3(256), 0, stream>>>(qh, khb, gq, gk, cosb, sinb);
  k_vtrans<<<dim3(32, 32), dim3(256), 0, stream>>>(vhb, vtb);
  k_attn<<<dim3(32, 32), dim3(256), 0, stream>>>(qh, khb, vtb, ao);
  k_gemm_o<<<dim3(32, 8, 1), dim3(256), 0, stream>>>(ao, wt + (size_t)3 * 1024 * 1024, bo, out);
}

// Round 6
// 143.224 us; speedup vs baseline: 1.4057x; 1.0546x over previous
//
#include <hip/hip_runtime.h>

typedef _Float16 f16;
typedef _Float16 f16x8 __attribute__((ext_vector_type(8)));
typedef _Float16 f16x4 __attribute__((ext_vector_type(4)));
typedef _Float16 f16x2 __attribute__((ext_vector_type(2)));
typedef float f32x4 __attribute__((ext_vector_type(4)));

#define MFMA(a, b, c) __builtin_amdgcn_mfma_f32_16x16x32_f16(a, b, c, 0, 0, 0)
#define PKRTZ(a, b) __builtin_bit_cast(f16x2, __builtin_amdgcn_cvt_pkrtz(a, b))

__device__ __forceinline__ void gload16(const void* g, void* l) {
  __builtin_amdgcn_global_load_lds((const __attribute__((address_space(1))) char*)g,
                                   (__attribute__((address_space(3))) char*)l, 16, 0, 0);
}

// B=2, T=2048, D=1024, H=16, DH=64

// ---------- prep: fp32 -> fp16 convert of hidden ----------
__global__ __launch_bounds__(256) void k_cvt_hidden(const float* __restrict__ x, f16* __restrict__ y) {
  int i = blockIdx.x * 256 + threadIdx.x;
  float4 v = ((const float4*)x)[i];
  f16x4 h; h[0] = (f16)v.x; h[1] = (f16)v.y; h[2] = (f16)v.z; h[3] = (f16)v.w;
  ((f16x4*)y)[i] = h;
}

// ---------- prep: transpose+convert weights [k][n] fp32 -> [n][k] fp16 ----------
__global__ __launch_bounds__(256) void k_cvt_w(const float* __restrict__ w0, const float* __restrict__ w1,
                                               const float* __restrict__ w2, const float* __restrict__ w3,
                                               f16* __restrict__ wt) {
  int z = blockIdx.z;
  const float* w = z == 0 ? w0 : z == 1 ? w1 : z == 2 ? w2 : w3;
  f16* dst = wt + (size_t)z * 1024 * 1024;
  __shared__ float tile[64][65];
  int t = threadIdx.x;
  int k0 = blockIdx.x * 64, n0 = blockIdx.y * 64;
  int cr = t >> 4, cc = (t & 15) * 4;
#pragma unroll
  for (int p = 0; p < 4; p++) {
    int r = cr + p * 16;
    float4 v = *(const float4*)&w[(size_t)(k0 + r) * 1024 + n0 + cc];
    tile[r][cc + 0] = v.x; tile[r][cc + 1] = v.y; tile[r][cc + 2] = v.z; tile[r][cc + 3] = v.w;
  }
  __syncthreads();
#pragma unroll
  for (int p = 0; p < 4; p++) {
    int nn = cr + p * 16;
    f16x4 h;
    h[0] = (f16)tile[cc + 0][nn]; h[1] = (f16)tile[cc + 1][nn];
    h[2] = (f16)tile[cc + 2][nn]; h[3] = (f16)tile[cc + 3][nn];
    *(f16x4*)&dst[(size_t)(n0 + nn) * 1024 + k0 + cc] = h;
  }
}

// ---------- GEMM core: C[128 rows @m0][128 cols] = A[M,K] @ Wrows^T, fp16 in, fp32 acc ----------
// Wrows points at the 128-row slice of W' [*][1024]; dst/bias already column-offset.
template <bool OUTF32>
__device__ __forceinline__ void gemm_core(const f16* __restrict__ A, const f16* __restrict__ Wrows,
                                          const float* __restrict__ bias, int m0,
                                          f16* __restrict__ oh, float* __restrict__ of) {
  __shared__ f16 Al[2][128 * 64];
  __shared__ f16 Bl[2][128 * 64];
  const int t = threadIdx.x;
  const int lane = t & 63, wid = t >> 6;
  const int lr = lane & 15, lg = lane >> 4;
  const int wm = wid >> 1, wn = wid & 1;
  const int lrow = lane >> 3;
  const int cb = (((lane & 7) ^ lrow) << 4);        // pre-swizzled source byte col

  f32x4 acc[4][4] = {};

  auto stage = [&](int k0, int bs) {
#pragma unroll
    for (int it = 0; it < 4; it++) {
      int rbase = it * 32 + wid * 8;                // wave-uniform
      int row = rbase + lrow;
      gload16((const char*)&A[(size_t)(m0 + row) * 1024 + k0] + cb, (char*)&Al[bs][0] + rbase * 128);
      gload16((const char*)&Wrows[(size_t)row * 1024 + k0] + cb, (char*)&Bl[bs][0] + rbase * 128);
    }
  };

  stage(0, 0);
  __syncthreads();
  int cur = 0;
  for (int k0 = 0; k0 < 1024; k0 += 64) {
    if (k0 + 64 < 1024) stage(k0 + 64, cur ^ 1);
    f16x8 af[2][4], bf[2][4];
#pragma unroll
    for (int x = 0; x < 4; x++) {
      int ra = wm * 64 + x * 16 + lr;
      int rb = wn * 64 + x * 16 + lr;
#pragma unroll
      for (int kh = 0; kh < 2; kh++) {
        int ca = (kh * 64 + lg * 16) ^ ((lr & 7) << 4);
        af[kh][x] = *(const f16x8*)((char*)&Al[cur][0] + ra * 128 + ca);
        bf[kh][x] = *(const f16x8*)((char*)&Bl[cur][0] + rb * 128 + ca);
      }
    }
    __builtin_amdgcn_s_setprio(1);
#pragma unroll
    for (int kh = 0; kh < 2; kh++)
#pragma unroll
      for (int mt = 0; mt < 4; mt++)
#pragma unroll
        for (int nt = 0; nt < 4; nt++)
          acc[mt][nt] = MFMA(af[kh][mt], bf[kh][nt], acc[mt][nt]);
    __builtin_amdgcn_s_setprio(0);
    __syncthreads();
    cur ^= 1;
  }
#pragma unroll
  for (int mt = 0; mt < 4; mt++) {
#pragma unroll
    for (int nt = 0; nt < 4; nt++) {
      int col = wn * 64 + nt * 16 + lr;             // local 0..127
      float bcol = bias[col];
#pragma unroll
      for (int e = 0; e < 4; e++) {
        int row = m0 + wm * 64 + mt * 16 + lg * 4 + e;
        float val = acc[mt][nt][e] + bcol;
        if (OUTF32) of[(size_t)row * 1024 + col] = val;
        else        oh[(size_t)row * 1024 + col] = (f16)val;
      }
    }
  }
}

// fused QKV: W' = wt as [3072][1024]; grid (32, 24)
__global__ __launch_bounds__(256, 2) void k_gemm_qkv(const f16* __restrict__ A, const f16* __restrict__ wt,
                                                     const float* __restrict__ bq, const float* __restrict__ bk,
                                                     const float* __restrict__ bv,
                                                     f16* __restrict__ q, f16* __restrict__ k, f16* __restrict__ v) {
  int n0 = blockIdx.y * 128;
  int zsel = n0 >> 10, cbs = n0 & 1023;
  const float* bias = (zsel == 0 ? bq : zsel == 1 ? bk : bv) + cbs;
  f16* dst = (zsel == 0 ? q : zsel == 1 ? k : v) + cbs;
  gemm_core<false>(A, wt + (size_t)n0 * 1024, bias, blockIdx.x * 128, dst, nullptr);
}

__global__ __launch_bounds__(256, 2) void k_gemm_o(const f16* __restrict__ A, const f16* __restrict__ wt3,
                                                   const float* __restrict__ bo, float* __restrict__ out) {
  int n0 = blockIdx.y * 128;
  gemm_core<true>(A, wt3 + (size_t)n0 * 1024, bo + n0, blockIdx.x * 128, nullptr, out + n0);
}

// ---------- RMSNorm + interleaved RoPE (in-place on fp16 q/k), fp32 math ----------
__global__ __launch_bounds__(256) void k_normrope(f16* __restrict__ qh, f16* __restrict__ kh,
                                                  const float* __restrict__ gq, const float* __restrict__ gk,
                                                  const float* __restrict__ cs, const float* __restrict__ sn) {
  int row = blockIdx.x, which = blockIdx.y;
  f16* buf = which ? kh : qh;
  const float* g = which ? gk : gq;
  int t = threadIdx.x, c4 = t * 4;
  f16x4 xv = *(const f16x4*)&buf[(size_t)row * 1024 + c4];
  float x0 = xv[0], x1 = xv[1], x2 = xv[2], x3 = xv[3];
  float ss = x0 * x0 + x1 * x1 + x2 * x2 + x3 * x3;
#pragma unroll
  for (int off = 1; off < 64; off <<= 1) ss += __shfl_xor(ss, off);
  __shared__ float red[4];
  if ((t & 63) == 0) red[t >> 6] = ss;
  __syncthreads();
  float inv = rsqrtf((red[0] + red[1] + red[2] + red[3]) * (1.0f / 1024.0f) + 1e-6f);
  int tt = row & 2047;
  float4 cv = *(const float4*)&cs[(size_t)tt * 1024 + c4];
  float4 sv = *(const float4*)&sn[(size_t)tt * 1024 + c4];
  float4 gv = *(const float4*)&g[c4];
  float y0 = x0 * inv * gv.x, y1 = x1 * inv * gv.y, y2 = x2 * inv * gv.z, y3 = x3 * inv * gv.w;
  f16x4 ov;
  ov[0] = (f16)(y0 * cv.x - y1 * sv.x);
  ov[1] = (f16)(y1 * cv.y + y0 * sv.y);
  ov[2] = (f16)(y2 * cv.z - y3 * sv.z);
  ov[3] = (f16)(y3 * cv.w + y2 * sv.w);
  *(f16x4*)&buf[(size_t)row * 1024 + c4] = ov;
}

// ---------- V transpose: [b,t,h*64+dh] -> [b,h,dh,t] ----------
__global__ __launch_bounds__(256) void k_vtrans(const f16* __restrict__ vh, f16* __restrict__ vt) {
  __shared__ f16 tile[64][65];
  int t = threadIdx.x;
  int t0 = blockIdx.x * 64;
  int bh = blockIdx.y;
  int b = bh >> 4, h = bh & 15;
  int rr = t >> 3, c8 = (t & 7) * 8;
#pragma unroll
  for (int p = 0; p < 2; p++) {
    int r = p * 32 + rr;
    f16x8 v = *(const f16x8*)&vh[(size_t)(b * 2048 + t0 + r) * 1024 + h * 64 + c8];
#pragma unroll
    for (int j = 0; j < 8; j++) tile[r][c8 + j] = v[j];
  }
  __syncthreads();
#pragma unroll
  for (int p = 0; p < 2; p++) {
    int dh = p * 32 + rr;
    f16x8 o;
#pragma unroll
    for (int j = 0; j < 8; j++) o[j] = tile[c8 + j][dh];
    *(f16x8*)&vt[((size_t)bh * 64 + dh) * 2048 + t0 + c8] = o;
  }
}

// ---------- flash attention v5: 32 q-rows/wave, ones-column row-sum ----------
// 4 waves x 32 q = 128 q-rows/block; KV-chunk 64; K/V frags read once, used by
// both q-groups (2x arithmetic intensity per LDS byte). Softmax denominator via
// PV against an all-ones virtual column (auto-rescaled with acc). Defer-max.
#define ASWZ(row) ((((row) & 3) | (((row) & 8) >> 1)) << 4)

__global__ __launch_bounds__(256, 2) void k_attn(const f16* __restrict__ qh, const f16* __restrict__ kh,
                                                 const f16* __restrict__ vt, f16* __restrict__ ao) {
  __shared__ f16 Kl[2][64 * 64];
  __shared__ f16 Vl[2][64 * 64];
  const int t = threadIdx.x;
  const int lane = t & 63, wid = t >> 6;
  const int lr = lane & 15, lg = lane >> 4;
  const int lgb = lg << 4;
  // XCD-aware remap: each XCD (raw%8) owns 4 bh groups -> KV fits its L2. 512 blocks.
  const int raw = blockIdx.x;
  const int mybh = ((raw & 7) << 2) | ((raw >> 3) & 3);
  const int myq = raw >> 5;                   // [0,16)
  const int b = mybh >> 4, h = mybh & 15;
  const int q0 = myq * 128 + wid * 32;
  const f16* Qb = qh + ((size_t)(b * 2048 + q0)) * 1024 + h * 64;
  f16x8 qf[2][2];
#pragma unroll
  for (int g = 0; g < 2; g++) {
    qf[g][0] = *(const f16x8*)&Qb[(size_t)(g * 16 + lr) * 1024 + lg * 8];
    qf[g][1] = *(const f16x8*)&Qb[(size_t)(g * 16 + lr) * 1024 + 32 + lg * 8];
  }
  const f16* Kg = kh + ((size_t)b * 2048) * 1024 + h * 64;
  const f16* Vg = vt + ((size_t)mybh) * 64 * 2048;
  const int lrow = lane >> 3;
  const int sg = (lane & 7) << 4;
  const float sc = 0.125f * 1.44269504088896340736f;
  float m[2] = {-1e30f, -1e30f};
  f32x4 acc[2][4] = {};
  f32x4 accl[2] = {};
  const f16 ov1 = (lr == 0) ? (f16)1.0f : (f16)0.0f;
  const f16x8 onesf = {ov1, ov1, ov1, ov1, ov1, ov1, ov1, ov1};

  auto stage = [&](int kvo, int bs) {
#pragma unroll
    for (int i = 0; i < 2; i++) {
      int rbase = (i * 4 + wid) * 8;          // wave-uniform
      int row = rbase + lrow;
      int cswz = sg ^ ASWZ(row);
      gload16((const char*)(Kg + (size_t)(kvo + row) * 1024) + cswz, (char*)&Kl[bs][0] + rbase * 128);
      gload16((const char*)(Vg + (size_t)row * 2048 + kvo) + cswz, (char*)&Vl[bs][0] + rbase * 128);
    }
  };

  stage(0, 0);
  __syncthreads();
  int cur = 0;

  for (int kv0 = 0; kv0 < 2048; kv0 += 64) {
    if (kv0 + 64 < 2048) stage(kv0 + 64, cur ^ 1);
    const char* Kb = (const char*)&Kl[cur][0];
    const char* Vb = (const char*)&Vl[cur][0];

    // S^T = K @ Q^T, permuted key rows; K frags shared by both q-groups.
    f32x4 s[2][4];
    __builtin_amdgcn_s_setprio(1);
#pragma unroll
    for (int ks = 0; ks < 4; ks++) {
      int key = ((lr >> 2) << 3) + (lr & 3) + ((ks & 1) << 2) + ((ks >> 1) << 5);
      int sw = ASWZ(key);
      f16x8 kf0 = *(const f16x8*)(Kb + key * 128 + (lgb ^ sw));
      f16x8 kf1 = *(const f16x8*)(Kb + key * 128 + ((64 + lgb) ^ sw));
#pragma unroll
      for (int g = 0; g < 2; g++) {
        f32x4 z = {};
        z = MFMA(kf0, qf[g][0], z);
        z = MFMA(kf1, qf[g][1], z);
        s[g][ks] = z;   // lane: S[qrow=lr(grp g)][key = lg*8+e+(ks&1)*4+(ks>>1)*32]
      }
    }
    __builtin_amdgcn_s_setprio(0);

    union U { f16x8 v; f16x2 h[4]; } u[2][2];
#pragma unroll
    for (int g = 0; g < 2; g++) {
      float smax = fmaxf(fmaxf(s[g][0][0], s[g][0][1]), s[g][0][2]);
      smax = fmaxf(fmaxf(smax, s[g][0][3]), s[g][1][0]);
      smax = fmaxf(fmaxf(smax, s[g][1][1]), s[g][1][2]);
      smax = fmaxf(fmaxf(smax, s[g][1][3]), s[g][2][0]);
      smax = fmaxf(fmaxf(smax, s[g][2][1]), s[g][2][2]);
      smax = fmaxf(fmaxf(smax, s[g][2][3]), s[g][3][0]);
      smax = fmaxf(fmaxf(smax, s[g][3][1]), s[g][3][2]);
      smax = fmaxf(smax, s[g][3][3]);
      smax = fmaxf(smax, __shfl_xor(smax, 16));
      smax = fmaxf(smax, __shfl_xor(smax, 32));
      float smc = smax * sc;

      if (!__all(smc - m[g] <= 8.f)) {        // defer-max
        float mn = fmaxf(m[g], smc);
        float al = exp2f(m[g] - mn);
        m[g] = mn;
        float alq[4];
#pragma unroll
        for (int e = 0; e < 4; e++) alq[e] = __shfl(al, lg * 4 + e);
#pragma unroll
        for (int ds = 0; ds < 4; ds++)
#pragma unroll
          for (int e = 0; e < 4; e++) acc[g][ds][e] *= alq[e];
#pragma unroll
        for (int e = 0; e < 4; e++) accl[g][e] *= alq[e];
      }

#pragma unroll
      for (int ks = 0; ks < 4; ks++) {
        float p0 = exp2f(fmaf(s[g][ks][0], sc, -m[g]));
        float p1 = exp2f(fmaf(s[g][ks][1], sc, -m[g]));
        float p2 = exp2f(fmaf(s[g][ks][2], sc, -m[g]));
        float p3 = exp2f(fmaf(s[g][ks][3], sc, -m[g]));
        u[g][ks >> 1].h[(ks & 1) * 2 + 0] = PKRTZ(p0, p1);
        u[g][ks >> 1].h[(ks & 1) * 2 + 1] = PKRTZ(p2, p3);
      }
    }

    // PV: V frags shared by both groups; denominator via ones-column.
    __builtin_amdgcn_s_setprio(1);
#pragma unroll
    for (int ds = 0; ds < 4; ds++) {
      int vrow = ds * 16 + lr;
      int sw = ASWZ(vrow);
      f16x8 vf0 = *(const f16x8*)(Vb + vrow * 128 + (lgb ^ sw));
      f16x8 vf1 = *(const f16x8*)(Vb + vrow * 128 + ((64 + lgb) ^ sw));
#pragma unroll
      for (int g = 0; g < 2; g++) {
        acc[g][ds] = MFMA(u[g][0].v, vf0, acc[g][ds]);
        acc[g][ds] = MFMA(u[g][1].v, vf1, acc[g][ds]);
      }
    }
#pragma unroll
    for (int g = 0; g < 2; g++) {
      accl[g] = MFMA(u[g][0].v, onesf, accl[g]);
      accl[g] = MFMA(u[g][1].v, onesf, accl[g]);
    }
    __builtin_amdgcn_s_setprio(0);

    __syncthreads();   // drains stage loads + protects LDS reuse
    cur ^= 1;
  }

#pragma unroll
  for (int g = 0; g < 2; g++) {
#pragma unroll
    for (int e = 0; e < 4; e++) {
      float lf = 1.f / __shfl(accl[g][e], lg << 4);   // l(row lg*4+e) lives on lane lg*16
      size_t row = (size_t)(b * 2048 + q0 + g * 16 + lg * 4 + e);
#pragma unroll
      for (int ds = 0; ds < 4; ds++)
        ao[row * 1024 + h * 64 + ds * 16 + lr] = (f16)(acc[g][ds][e] * lf);
    }
  }
}

extern "C" void kernel_launch(void* const* d_in, const int* in_sizes, int n_in,
                              void* d_out, int out_size, void* d_ws, size_t ws_size,
                              hipStream_t stream) {
  const float* hid  = (const float*)d_in[0];
  const float* cosb = (const float*)d_in[1];
  const float* sinb = (const float*)d_in[2];
  const float* wq = (const float*)d_in[3];
  const float* bq = (const float*)d_in[4];
  const float* wk = (const float*)d_in[5];
  const float* bk = (const float*)d_in[6];
  const float* wv = (const float*)d_in[7];
  const float* bv = (const float*)d_in[8];
  const float* gq = (const float*)d_in[9];
  const float* gk = (const float*)d_in[10];
  const float* wo = (const float*)d_in[11];
  const float* bo = (const float*)d_in[12];
  float* out = (float*)d_out;

  char* ws = (char*)d_ws;
  f16* aH  = (f16*)(ws);                          // 8 MB: hidden fp16 [4096][1024]
  f16* wt  = (f16*)(ws + ((size_t)8 << 20));      // 8 MB: 4 weights transposed [n][k] fp16
  f16* qh  = (f16*)(ws + ((size_t)16 << 20));     // 8 MB
  f16* khb = (f16*)(ws + ((size_t)24 << 20));     // 8 MB
  f16* vhb = (f16*)(ws + ((size_t)32 << 20));     // 8 MB
  f16* vtb = (f16*)(ws + ((size_t)40 << 20));     // 8 MB: V^T [b,h,dh,t]
  f16* ao  = (f16*)(ws + ((size_t)48 << 20));     // 8 MB: attention out [4096][1024]

  k_cvt_hidden<<<dim3(4096), dim3(256), 0, stream>>>(hid, aH);
  k_cvt_w<<<dim3(16, 16, 4), dim3(256), 0, stream>>>(wq, wk, wv, wo, wt);
  k_gemm_qkv<<<dim3(32, 24), dim3(256), 0, stream>>>(aH, wt, bq, bk, bv, qh, khb, vhb);
  k_normrope<<<dim3(4096, 2), dim3(256), 0, stream>>>(qh, khb, gq, gk, cosb, sinb);
  k_vtrans<<<dim3(32, 32), dim3(256), 0, stream>>>(vhb, vtb);
  k_attn<<<dim3(512), dim3(256), 0, stream>>>(qh, khb, vtb, ao);
  k_gemm_o<<<dim3(32, 8), dim3(256), 0, stream>>>(ao, wt + (size_t)3 * 1024 * 1024, bo, out);
}